// Round 1
// baseline (1321.140 us; speedup 1.0000x reference)
//
#include <hip/hip_runtime.h>
#include <cstdio>
#include <cstdint>

#define N_TOK 16384
#define DIM   1024
#define NEXP  8
#define HID   2048

typedef __attribute__((ext_vector_type(8))) short bf16x8;
typedef __attribute__((ext_vector_type(4))) float f32x4;

__device__ inline ushort f2bf(float f) {
  uint32_t u = __float_as_uint(f);
  uint32_t r = (u + 0x7fffu + ((u >> 16) & 1u)) >> 16;
  return (ushort)r;
}

// ---------------- router: fp32 logits, top-2, renormalized gates ----------------
__global__ __launch_bounds__(256) void router_kernel(
    const float* __restrict__ x, const float* __restrict__ rw,
    const float* __restrict__ rb, int* __restrict__ cnt,
    int* __restrict__ tok_e, float* __restrict__ tok_g) {
  __shared__ float wT[NEXP][DIM];  // 32KB, transposed for conflict-free reads
  for (int i = threadIdx.x; i < NEXP * DIM; i += 256) {
    int d = i >> 3, e = i & 7;
    wT[e][d] = rw[i];
  }
  __syncthreads();
  int wave = threadIdx.x >> 6, lane = threadIdx.x & 63;
  int t0 = blockIdx.x * 16 + wave * 4;
  for (int it = 0; it < 4; ++it) {
    int t = t0 + it;
    const float* xr = x + (size_t)t * DIM;
    float acc[NEXP];
#pragma unroll
    for (int e = 0; e < NEXP; ++e) acc[e] = 0.f;
#pragma unroll
    for (int j = 0; j < DIM / 64; ++j) {
      int d = lane + j * 64;           // lane-strided: coalesced global, bank-free LDS
      float xv = xr[d];
#pragma unroll
      for (int e = 0; e < NEXP; ++e) acc[e] += xv * wT[e][d];
    }
    float lg[NEXP];
#pragma unroll
    for (int e = 0; e < NEXP; ++e) {
      float v = acc[e];
      for (int o = 32; o > 0; o >>= 1) v += __shfl_xor(v, o);
      lg[e] = v + rb[e];
    }
    // top-2, ties -> lower index (matches lax.top_k)
    int i0 = 0; float m0 = lg[0];
#pragma unroll
    for (int e = 1; e < NEXP; ++e) if (lg[e] > m0) { m0 = lg[e]; i0 = e; }
    int i1 = -1; float m1 = -3.4e38f;
#pragma unroll
    for (int e = 0; e < NEXP; ++e) if (e != i0 && lg[e] > m1) { m1 = lg[e]; i1 = e; }
    // renormalized top-2 softmax: denominator cancels
    float g0 = 1.f / (1.f + expf(m1 - m0));
    float g1 = 1.f - g0;
    if (lane == 0) {
      tok_e[2 * t] = i0; tok_e[2 * t + 1] = i1;
      tok_g[2 * t] = g0; tok_g[2 * t + 1] = g1;
      atomicAdd(&cnt[i0], 1); atomicAdd(&cnt[i1], 1);
    }
  }
}

__global__ void scan_kernel(const int* __restrict__ cnt, int* __restrict__ offs,
                            int* __restrict__ cursor) {
  if (threadIdx.x == 0) {
    int s = 0;
    for (int e = 0; e < NEXP; ++e) { offs[e] = s; cursor[e] = s; s += cnt[e]; }
    offs[NEXP] = s;
  }
}

__global__ __launch_bounds__(256) void gather_kernel(
    const int* __restrict__ tok_e, const float* __restrict__ tok_g,
    int* __restrict__ cursor, int* __restrict__ slot_token,
    float* __restrict__ slot_gate) {
  int t = blockIdx.x * 256 + threadIdx.x;
  if (t >= N_TOK) return;
#pragma unroll
  for (int k = 0; k < 2; ++k) {
    int e = tok_e[2 * t + k];
    int s = atomicAdd(&cursor[e], 1);
    slot_token[s] = t;
    slot_gate[s] = tok_g[2 * t + k];
  }
}

// ---------------- transpose + f32->bf16 convert (per expert) ----------------
// src: [E][R][C] f32   dst: [E][C][R] bf16
template <int R, int C>
__global__ __launch_bounds__(256) void transpose_cvt(const float* __restrict__ src,
                                                     ushort* __restrict__ dst) {
  __shared__ float tile[64][65];
  int e = blockIdx.z;
  const float* s = src + (size_t)e * R * C;
  ushort* d = dst + (size_t)e * R * C;
  int r0 = blockIdx.y * 64, c0 = blockIdx.x * 64;
#pragma unroll
  for (int i = 0; i < 16; ++i) {
    int idx = i * 256 + threadIdx.x;
    int r = idx >> 6, c = idx & 63;
    tile[r][c] = s[(size_t)(r0 + r) * C + c0 + c];
  }
  __syncthreads();
#pragma unroll
  for (int i = 0; i < 16; ++i) {
    int idx = i * 256 + threadIdx.x;
    int orow = idx >> 6, oc = idx & 63;
    d[(size_t)(c0 + orow) * R + r0 + oc] = f2bf(tile[oc][orow]);
  }
}

// ---------------- grouped GEMM1: h = relu(x_gather @ w1T^T + b1) ----------------
// A: gathered x rows (f32 -> bf16 on stage), B: w1T[e] ([H][D], k-contiguous)
__global__ __launch_bounds__(256) void gemm1_kernel(
    const float* __restrict__ x, const ushort* __restrict__ w1T,
    const float* __restrict__ b1, const int* __restrict__ offs,
    const int* __restrict__ slot_token, ushort* __restrict__ h) {
  int e = blockIdx.z;
  int off = offs[e];
  int cn = offs[e + 1] - off;
  int mt = blockIdx.y;
  if (mt * 128 >= cn) return;
  int nt = blockIdx.x;
  __shared__ __align__(16) ushort Ab[128][72];
  __shared__ __align__(16) ushort Bb[128][72];
  __shared__ int toks[128];
  int tid = threadIdx.x;
  if (tid < 128) {
    int r = mt * 128 + tid;
    toks[tid] = slot_token[off + (r < cn ? r : 0)];
  }
  __syncthreads();
  int wave = tid >> 6, lane = tid & 63;
  int wm = (wave >> 1) * 64, wn = (wave & 1) * 64;
  const ushort* Bsrc = w1T + (size_t)e * HID * DIM + (size_t)nt * 128 * DIM;
  f32x4 acc[4][4];
#pragma unroll
  for (int i = 0; i < 4; ++i)
#pragma unroll
    for (int j = 0; j < 4; ++j) acc[i][j] = (f32x4){0.f, 0.f, 0.f, 0.f};

  for (int kt = 0; kt < DIM / 64; ++kt) {
    int k0 = kt * 64;
    // stage A: 128 rows x 64 f32 -> bf16
#pragma unroll
    for (int i = 0; i < 8; ++i) {
      int idx = i * 256 + tid;
      int r = idx >> 4, sg = idx & 15;
      float4 v = *(const float4*)(x + (size_t)toks[r] * DIM + k0 + sg * 4);
      ushort4 u = { f2bf(v.x), f2bf(v.y), f2bf(v.z), f2bf(v.w) };
      *(ushort4*)&Ab[r][sg * 4] = u;
    }
    // stage B: 128 rows x 64 bf16 copy
#pragma unroll
    for (int i = 0; i < 4; ++i) {
      int idx = i * 256 + tid;
      int r = idx >> 3, sg = idx & 7;
      int4 v = *(const int4*)(Bsrc + (size_t)r * DIM + k0 + sg * 8);
      *(int4*)&Bb[r][sg * 8] = v;
    }
    __syncthreads();
#pragma unroll
    for (int kk = 0; kk < 2; ++kk) {
      int krow = kk * 32 + (lane >> 4) * 8;
      bf16x8 a[4], b[4];
#pragma unroll
      for (int mi = 0; mi < 4; ++mi) a[mi] = *(const bf16x8*)&Ab[wm + mi * 16 + (lane & 15)][krow];
#pragma unroll
      for (int ni = 0; ni < 4; ++ni) b[ni] = *(const bf16x8*)&Bb[wn + ni * 16 + (lane & 15)][krow];
#pragma unroll
      for (int mi = 0; mi < 4; ++mi)
#pragma unroll
        for (int ni = 0; ni < 4; ++ni)
          acc[mi][ni] = __builtin_amdgcn_mfma_f32_16x16x32_bf16(a[mi], b[ni], acc[mi][ni], 0, 0, 0);
    }
    __syncthreads();
  }
  int ln = lane & 15, lg4 = (lane >> 4) * 4;
#pragma unroll
  for (int ni = 0; ni < 4; ++ni) {
    int col = nt * 128 + wn + ni * 16 + ln;
    float bias = b1[(size_t)e * HID + col];
#pragma unroll
    for (int mi = 0; mi < 4; ++mi) {
#pragma unroll
      for (int rg = 0; rg < 4; ++rg) {
        int r = mt * 128 + wm + mi * 16 + lg4 + rg;
        if (r < cn) {
          float v = acc[mi][ni][rg] + bias;
          h[(size_t)(off + r) * HID + col] = f2bf(fmaxf(v, 0.f));
        }
      }
    }
  }
}

// ---------------- grouped GEMM2: out[token] += gate * (h @ w2T^T + b2) ----------------
__global__ __launch_bounds__(256) void gemm2_kernel(
    const ushort* __restrict__ h, const ushort* __restrict__ w2T,
    const float* __restrict__ b2, const int* __restrict__ offs,
    const int* __restrict__ slot_token, const float* __restrict__ slot_gate,
    float* __restrict__ out) {
  int e = blockIdx.z;
  int off = offs[e];
  int cn = offs[e + 1] - off;
  int mt = blockIdx.y;
  if (mt * 128 >= cn) return;
  int nt = blockIdx.x;  // 0..7 over DIM
  __shared__ __align__(16) ushort Ab[128][72];
  __shared__ __align__(16) ushort Bb[128][72];
  __shared__ int toks[128];
  __shared__ float gts[128];
  int tid = threadIdx.x;
  if (tid < 128) {
    int r = mt * 128 + tid;
    int s = off + (r < cn ? r : 0);
    toks[tid] = slot_token[s];
    gts[tid] = slot_gate[s];
  }
  __syncthreads();
  int wave = tid >> 6, lane = tid & 63;
  int wm = (wave >> 1) * 64, wn = (wave & 1) * 64;
  const ushort* Bsrc = w2T + (size_t)e * DIM * HID + (size_t)nt * 128 * HID;
  f32x4 acc[4][4];
#pragma unroll
  for (int i = 0; i < 4; ++i)
#pragma unroll
    for (int j = 0; j < 4; ++j) acc[i][j] = (f32x4){0.f, 0.f, 0.f, 0.f};

  for (int kt = 0; kt < HID / 64; ++kt) {
    int k0 = kt * 64;
    // stage A: 128 rows x 64 bf16 from h (slot rows)
#pragma unroll
    for (int i = 0; i < 4; ++i) {
      int idx = i * 256 + tid;
      int r = idx >> 3, sg = idx & 7;
      int rr = mt * 128 + r; rr = rr < cn ? rr : 0;
      int4 v = *(const int4*)(h + (size_t)(off + rr) * HID + k0 + sg * 8);
      *(int4*)&Ab[r][sg * 8] = v;
    }
    // stage B: 128 rows x 64 bf16 from w2T
#pragma unroll
    for (int i = 0; i < 4; ++i) {
      int idx = i * 256 + tid;
      int r = idx >> 3, sg = idx & 7;
      int4 v = *(const int4*)(Bsrc + (size_t)r * HID + k0 + sg * 8);
      *(int4*)&Bb[r][sg * 8] = v;
    }
    __syncthreads();
#pragma unroll
    for (int kk = 0; kk < 2; ++kk) {
      int krow = kk * 32 + (lane >> 4) * 8;
      bf16x8 a[4], b[4];
#pragma unroll
      for (int mi = 0; mi < 4; ++mi) a[mi] = *(const bf16x8*)&Ab[wm + mi * 16 + (lane & 15)][krow];
#pragma unroll
      for (int ni = 0; ni < 4; ++ni) b[ni] = *(const bf16x8*)&Bb[wn + ni * 16 + (lane & 15)][krow];
#pragma unroll
      for (int mi = 0; mi < 4; ++mi)
#pragma unroll
        for (int ni = 0; ni < 4; ++ni)
          acc[mi][ni] = __builtin_amdgcn_mfma_f32_16x16x32_bf16(a[mi], b[ni], acc[mi][ni], 0, 0, 0);
    }
    __syncthreads();
  }
  int ln = lane & 15, lg4 = (lane >> 4) * 4;
#pragma unroll
  for (int ni = 0; ni < 4; ++ni) {
    int col = nt * 128 + wn + ni * 16 + ln;
    float bias = b2[(size_t)e * DIM + col];
#pragma unroll
    for (int mi = 0; mi < 4; ++mi) {
#pragma unroll
      for (int rg = 0; rg < 4; ++rg) {
        int rl = wm + mi * 16 + lg4 + rg;
        int r = mt * 128 + rl;
        if (r < cn) {
          float v = gts[rl] * (acc[mi][ni][rg] + bias);
          atomicAdd(&out[(size_t)toks[rl] * DIM + col], v);
        }
      }
    }
  }
}

extern "C" void kernel_launch(void* const* d_in, const int* in_sizes, int n_in,
                              void* d_out, int out_size, void* d_ws, size_t ws_size,
                              hipStream_t stream) {
  const float* x  = (const float*)d_in[0];
  const float* rw = (const float*)d_in[1];
  const float* rb = (const float*)d_in[2];
  const float* w1 = (const float*)d_in[3];
  const float* b1 = (const float*)d_in[4];
  const float* w2 = (const float*)d_in[5];
  const float* b2 = (const float*)d_in[6];
  float* out = (float*)d_out;
  char* ws = (char*)d_ws;

  // workspace layout
  const size_t o_ctrl = 0;                       // cnt[8], cursor[8], offs[9]
  const size_t o_toke = 256;                     // N*2 int
  const size_t o_tokg = o_toke + 131072;         // N*2 f32
  const size_t o_stok = o_tokg + 131072;         // 32768 int
  const size_t o_sgat = o_stok + 131072;         // 32768 f32
  const size_t o_w1T  = o_sgat + 131072;         // E*H*D bf16 = 33.5MB
  const size_t o_w2T  = o_w1T + (size_t)NEXP * HID * DIM * 2;
  const size_t o_h    = o_w2T + (size_t)NEXP * DIM * HID * 2;
  const size_t required = o_h + (size_t)N_TOK * 2 * HID * 2;  // ~202 MB
  if (ws_size < required) {
    fprintf(stderr, "kernel_launch: ws too small: have %zu need %zu\n", ws_size, required);
    return;
  }
  int* cnt        = (int*)(ws + o_ctrl);
  int* cursor     = cnt + 8;
  int* offs       = cnt + 16;
  int* tok_e      = (int*)(ws + o_toke);
  float* tok_g    = (float*)(ws + o_tokg);
  int* slot_token = (int*)(ws + o_stok);
  float* slot_gate= (float*)(ws + o_sgat);
  ushort* w1T     = (ushort*)(ws + o_w1T);
  ushort* w2T     = (ushort*)(ws + o_w2T);
  ushort* hbuf    = (ushort*)(ws + o_h);

  hipMemsetAsync(d_out, 0, (size_t)out_size * 4, stream);
  hipMemsetAsync(ws + o_ctrl, 0, 64, stream);

  // weight transposes: w1 [E][D][H] -> w1T [E][H][D]; w2 [E][H][D] -> w2T [E][D][H]
  transpose_cvt<DIM, HID><<<dim3(HID / 64, DIM / 64, NEXP), 256, 0, stream>>>(w1, w1T);
  transpose_cvt<HID, DIM><<<dim3(DIM / 64, HID / 64, NEXP), 256, 0, stream>>>(w2, w2T);

  router_kernel<<<N_TOK / 16, 256, 0, stream>>>(x, rw, rb, cnt, tok_e, tok_g);
  scan_kernel<<<1, 64, 0, stream>>>(cnt, offs, cursor);
  gather_kernel<<<N_TOK / 256, 256, 0, stream>>>(tok_e, tok_g, cursor, slot_token, slot_gate);

  // grouped GEMMs (grid sized for worst-case expert imbalance; blocks early-exit)
  gemm1_kernel<<<dim3(HID / 128, N_TOK / 128, NEXP), 256, 0, stream>>>(
      x, w1T, b1, offs, slot_token, hbuf);
  gemm2_kernel<<<dim3(DIM / 128, N_TOK / 128, NEXP), 256, 0, stream>>>(
      hbuf, w2T, b2, offs, slot_token, slot_gate, out);
}

// Round 2
// 1277.022 us; speedup vs baseline: 1.0345x; 1.0345x over previous
//
#include <hip/hip_runtime.h>
#include <cstdio>
#include <cstdint>

#define N_TOK 16384
#define DIM   1024
#define NEXP  8
#define HID   2048

typedef __attribute__((ext_vector_type(8))) short bf16x8;
typedef __attribute__((ext_vector_type(4))) float f32x4;

__device__ inline ushort f2bf(float f) {
  uint32_t u = __float_as_uint(f);
  uint32_t r = (u + 0x7fffu + ((u >> 16) & 1u)) >> 16;
  return (ushort)r;
}

// async global->LDS, 16B per lane; LDS dest is wave-uniform base + lane*16
__device__ __forceinline__ void gload_lds16(const void* g, void* l) {
  __builtin_amdgcn_global_load_lds((const __attribute__((address_space(1))) void*)g,
                                   (__attribute__((address_space(3))) void*)l, 16, 0, 0);
}

// ---------------- x f32 -> bf16 pre-convert ----------------
__global__ __launch_bounds__(256) void xcvt_kernel(const float* __restrict__ x,
                                                   ushort* __restrict__ xb) {
  size_t i = (size_t)blockIdx.x * 256 + threadIdx.x;  // 8 elems/thread
  float4 v0 = *(const float4*)(x + i * 8);
  float4 v1 = *(const float4*)(x + i * 8 + 4);
  ushort4 a = { f2bf(v0.x), f2bf(v0.y), f2bf(v0.z), f2bf(v0.w) };
  ushort4 b = { f2bf(v1.x), f2bf(v1.y), f2bf(v1.z), f2bf(v1.w) };
  *(ushort4*)(xb + i * 8) = a;
  *(ushort4*)(xb + i * 8 + 4) = b;
}

// ---------------- router: fp32 logits, top-2, renormalized gates ----------------
__global__ __launch_bounds__(256) void router_kernel(
    const float* __restrict__ x, const float* __restrict__ rw,
    const float* __restrict__ rb, int* __restrict__ cnt,
    int* __restrict__ tok_e, float* __restrict__ tok_g) {
  __shared__ float wT[NEXP][DIM];
  for (int i = threadIdx.x; i < NEXP * DIM; i += 256) {
    int d = i >> 3, e = i & 7;
    wT[e][d] = rw[i];
  }
  __syncthreads();
  int wave = threadIdx.x >> 6, lane = threadIdx.x & 63;
  int t0 = blockIdx.x * 16 + wave * 4;
  for (int it = 0; it < 4; ++it) {
    int t = t0 + it;
    const float* xr = x + (size_t)t * DIM;
    float acc[NEXP];
#pragma unroll
    for (int e = 0; e < NEXP; ++e) acc[e] = 0.f;
#pragma unroll
    for (int j = 0; j < DIM / 64; ++j) {
      int d = lane + j * 64;
      float xv = xr[d];
#pragma unroll
      for (int e = 0; e < NEXP; ++e) acc[e] += xv * wT[e][d];
    }
    float lg[NEXP];
#pragma unroll
    for (int e = 0; e < NEXP; ++e) {
      float v = acc[e];
      for (int o = 32; o > 0; o >>= 1) v += __shfl_xor(v, o);
      lg[e] = v + rb[e];
    }
    int i0 = 0; float m0 = lg[0];
#pragma unroll
    for (int e = 1; e < NEXP; ++e) if (lg[e] > m0) { m0 = lg[e]; i0 = e; }
    int i1 = -1; float m1 = -3.4e38f;
#pragma unroll
    for (int e = 0; e < NEXP; ++e) if (e != i0 && lg[e] > m1) { m1 = lg[e]; i1 = e; }
    float g0 = 1.f / (1.f + expf(m1 - m0));
    float g1 = 1.f - g0;
    if (lane == 0) {
      tok_e[2 * t] = i0; tok_e[2 * t + 1] = i1;
      tok_g[2 * t] = g0; tok_g[2 * t + 1] = g1;
      atomicAdd(&cnt[i0], 1); atomicAdd(&cnt[i1], 1);
    }
  }
}

__global__ void scan_kernel(const int* __restrict__ cnt, int* __restrict__ offs,
                            int* __restrict__ cursor) {
  if (threadIdx.x == 0) {
    int s = 0;
    for (int e = 0; e < NEXP; ++e) { offs[e] = s; cursor[e] = s; s += cnt[e]; }
    offs[NEXP] = s;
  }
}

__global__ __launch_bounds__(256) void gather_kernel(
    const int* __restrict__ tok_e, const float* __restrict__ tok_g,
    int* __restrict__ cursor, int* __restrict__ slot_token,
    float* __restrict__ slot_gate) {
  int t = blockIdx.x * 256 + threadIdx.x;
  if (t >= N_TOK) return;
#pragma unroll
  for (int k = 0; k < 2; ++k) {
    int e = tok_e[2 * t + k];
    int s = atomicAdd(&cursor[e], 1);
    slot_token[s] = t;
    slot_gate[s] = tok_g[2 * t + k];
  }
}

// ---------------- transpose + f32->bf16 convert (per expert) ----------------
// src: [E][R][C] f32   dst: [E][C][R] bf16
template <int R, int C>
__global__ __launch_bounds__(256) void transpose_cvt(const float* __restrict__ src,
                                                     ushort* __restrict__ dst) {
  __shared__ float tile[64][65];
  int e = blockIdx.z;
  const float* s = src + (size_t)e * R * C;
  ushort* d = dst + (size_t)e * R * C;
  int r0 = blockIdx.y * 64, c0 = blockIdx.x * 64;
#pragma unroll
  for (int i = 0; i < 16; ++i) {
    int idx = i * 256 + threadIdx.x;
    int r = idx >> 6, c = idx & 63;
    tile[r][c] = s[(size_t)(r0 + r) * C + c0 + c];
  }
  __syncthreads();
#pragma unroll
  for (int i = 0; i < 16; ++i) {
    int idx = i * 256 + threadIdx.x;
    int orow = idx >> 6, oc = idx & 63;
    d[(size_t)(c0 + orow) * R + r0 + oc] = f2bf(tile[oc][orow]);
  }
}

// ---------------- grouped GEMM1: h = relu(x_gather @ w1T^T + b1) ----------------
// m97 structure: global_load_lds(16B) staging, linear LDS, 2 barriers/K-step.
__global__ __launch_bounds__(256) void gemm1_kernel(
    const ushort* __restrict__ xb, const ushort* __restrict__ w1T,
    const float* __restrict__ b1, const int* __restrict__ offs,
    const int* __restrict__ slot_token, ushort* __restrict__ h) {
  int e = blockIdx.z;
  int off = offs[e];
  int cn = offs[e + 1] - off;
  int mt = blockIdx.y;
  if (mt * 128 >= cn) return;
  int nt = blockIdx.x;
  __shared__ __align__(16) ushort Ab[128 * 64];
  __shared__ __align__(16) ushort Bb[128 * 64];
  __shared__ int toks[128];
  int tid = threadIdx.x;
  if (tid < 128) {
    int r = mt * 128 + tid;
    toks[tid] = slot_token[off + (r < cn ? r : 0)];
  }
  __syncthreads();
  int wave = tid >> 6, lane = tid & 63;
  int wm = (wave >> 1) * 64, wn = (wave & 1) * 64;
  // staging geometry: wave w owns chunks c=w*4..w*4+3 of both A and B tiles.
  // chunk c = rows c*8..c*8+7, lane covers row c*8+(lane>>3), col (lane&7)*8 (16B)
  const ushort* Bsrc = w1T + (size_t)e * HID * DIM + (size_t)nt * 128 * DIM;
  int colel = (lane & 7) * 8;
  const ushort* agp[4];
  const ushort* bgp[4];
#pragma unroll
  for (int c = 0; c < 4; ++c) {
    int row = (wave * 4 + c) * 8 + (lane >> 3);
    agp[c] = xb + (size_t)toks[row] * DIM + colel;
    bgp[c] = Bsrc + (size_t)row * DIM + colel;
  }
  f32x4 acc[4][4];
#pragma unroll
  for (int i = 0; i < 4; ++i)
#pragma unroll
    for (int j = 0; j < 4; ++j) acc[i][j] = (f32x4){0.f, 0.f, 0.f, 0.f};

  for (int kt = 0; kt < DIM / 64; ++kt) {
#pragma unroll
    for (int c = 0; c < 4; ++c) {
      gload_lds16(agp[c], &Ab[(wave * 4 + c) * 512]);
      gload_lds16(bgp[c], &Bb[(wave * 4 + c) * 512]);
      agp[c] += 64; bgp[c] += 64;
    }
    asm volatile("s_waitcnt vmcnt(0)" ::: "memory");
    __syncthreads();
#pragma unroll
    for (int kk = 0; kk < 2; ++kk) {
      int colb = kk * 32 + (lane >> 4) * 8;
      bf16x8 a[4], b[4];
#pragma unroll
      for (int mi = 0; mi < 4; ++mi)
        a[mi] = *(const bf16x8*)&Ab[(wm + mi * 16 + (lane & 15)) * 64 + colb];
#pragma unroll
      for (int ni = 0; ni < 4; ++ni)
        b[ni] = *(const bf16x8*)&Bb[(wn + ni * 16 + (lane & 15)) * 64 + colb];
#pragma unroll
      for (int mi = 0; mi < 4; ++mi)
#pragma unroll
        for (int ni = 0; ni < 4; ++ni)
          acc[mi][ni] = __builtin_amdgcn_mfma_f32_16x16x32_bf16(a[mi], b[ni], acc[mi][ni], 0, 0, 0);
    }
    __syncthreads();
  }
  int ln = lane & 15, lg4 = (lane >> 4) * 4;
#pragma unroll
  for (int ni = 0; ni < 4; ++ni) {
    int col = nt * 128 + wn + ni * 16 + ln;
    float bias = b1[(size_t)e * HID + col];
#pragma unroll
    for (int mi = 0; mi < 4; ++mi) {
#pragma unroll
      for (int rg = 0; rg < 4; ++rg) {
        int r = mt * 128 + wm + mi * 16 + lg4 + rg;
        if (r < cn) {
          float v = acc[mi][ni][rg] + bias;
          h[(size_t)(off + r) * HID + col] = f2bf(fmaxf(v, 0.f));
        }
      }
    }
  }
}

// ---------------- grouped GEMM2: out[token] += gate * (h @ w2T^T + b2) ----------------
__global__ __launch_bounds__(256) void gemm2_kernel(
    const ushort* __restrict__ h, const ushort* __restrict__ w2T,
    const float* __restrict__ b2, const int* __restrict__ offs,
    const int* __restrict__ slot_token, const float* __restrict__ slot_gate,
    float* __restrict__ out) {
  int e = blockIdx.z;
  int off = offs[e];
  int cn = offs[e + 1] - off;
  int mt = blockIdx.y;
  if (mt * 128 >= cn) return;
  int nt = blockIdx.x;  // 0..7 over DIM
  __shared__ __align__(16) ushort Ab[128 * 64];
  __shared__ __align__(16) ushort Bb[128 * 64];
  __shared__ int toks[128];
  __shared__ float gts[128];
  int tid = threadIdx.x;
  if (tid < 128) {
    int r = mt * 128 + tid;
    int s = off + (r < cn ? r : 0);
    toks[tid] = slot_token[s];
    gts[tid] = slot_gate[s];
  }
  __syncthreads();
  int wave = tid >> 6, lane = tid & 63;
  int wm = (wave >> 1) * 64, wn = (wave & 1) * 64;
  const ushort* Bsrc = w2T + (size_t)e * DIM * HID + (size_t)nt * 128 * HID;
  int colel = (lane & 7) * 8;
  const ushort* agp[4];
  const ushort* bgp[4];
#pragma unroll
  for (int c = 0; c < 4; ++c) {
    int row = (wave * 4 + c) * 8 + (lane >> 3);
    int rr = mt * 128 + row; rr = rr < cn ? rr : 0;
    agp[c] = h + (size_t)(off + rr) * HID + colel;
    bgp[c] = Bsrc + (size_t)row * HID + colel;
  }
  f32x4 acc[4][4];
#pragma unroll
  for (int i = 0; i < 4; ++i)
#pragma unroll
    for (int j = 0; j < 4; ++j) acc[i][j] = (f32x4){0.f, 0.f, 0.f, 0.f};

  for (int kt = 0; kt < HID / 64; ++kt) {
#pragma unroll
    for (int c = 0; c < 4; ++c) {
      gload_lds16(agp[c], &Ab[(wave * 4 + c) * 512]);
      gload_lds16(bgp[c], &Bb[(wave * 4 + c) * 512]);
      agp[c] += 64; bgp[c] += 64;
    }
    asm volatile("s_waitcnt vmcnt(0)" ::: "memory");
    __syncthreads();
#pragma unroll
    for (int kk = 0; kk < 2; ++kk) {
      int colb = kk * 32 + (lane >> 4) * 8;
      bf16x8 a[4], b[4];
#pragma unroll
      for (int mi = 0; mi < 4; ++mi)
        a[mi] = *(const bf16x8*)&Ab[(wm + mi * 16 + (lane & 15)) * 64 + colb];
#pragma unroll
      for (int ni = 0; ni < 4; ++ni)
        b[ni] = *(const bf16x8*)&Bb[(wn + ni * 16 + (lane & 15)) * 64 + colb];
#pragma unroll
      for (int mi = 0; mi < 4; ++mi)
#pragma unroll
        for (int ni = 0; ni < 4; ++ni)
          acc[mi][ni] = __builtin_amdgcn_mfma_f32_16x16x32_bf16(a[mi], b[ni], acc[mi][ni], 0, 0, 0);
    }
    __syncthreads();
  }
  int ln = lane & 15, lg4 = (lane >> 4) * 4;
#pragma unroll
  for (int ni = 0; ni < 4; ++ni) {
    int col = nt * 128 + wn + ni * 16 + ln;
    float bias = b2[(size_t)e * DIM + col];
#pragma unroll
    for (int mi = 0; mi < 4; ++mi) {
#pragma unroll
      for (int rg = 0; rg < 4; ++rg) {
        int rl = wm + mi * 16 + lg4 + rg;
        int r = mt * 128 + rl;
        if (r < cn) {
          float v = gts[rl] * (acc[mi][ni][rg] + bias);
          atomicAdd(&out[(size_t)toks[rl] * DIM + col], v);
        }
      }
    }
  }
}

extern "C" void kernel_launch(void* const* d_in, const int* in_sizes, int n_in,
                              void* d_out, int out_size, void* d_ws, size_t ws_size,
                              hipStream_t stream) {
  const float* x  = (const float*)d_in[0];
  const float* rw = (const float*)d_in[1];
  const float* rb = (const float*)d_in[2];
  const float* w1 = (const float*)d_in[3];
  const float* b1 = (const float*)d_in[4];
  const float* w2 = (const float*)d_in[5];
  const float* b2 = (const float*)d_in[6];
  float* out = (float*)d_out;
  char* ws = (char*)d_ws;

  // workspace layout (xb aliases w2T: xb dead after gemm1, w2T created after)
  const size_t o_ctrl = 0;                       // cnt[8], cursor[8], offs[9]
  const size_t o_toke = 256;                     // N*2 int
  const size_t o_tokg = o_toke + 131072;         // N*2 f32
  const size_t o_stok = o_tokg + 131072;         // 32768 int
  const size_t o_sgat = o_stok + 131072;         // 32768 f32
  const size_t o_xb   = o_sgat + 131072;         // N*D bf16 = 33.5MB (== w2T size)
  const size_t o_w1T  = o_xb + (size_t)N_TOK * DIM * 2;
  const size_t o_h    = o_w1T + (size_t)NEXP * HID * DIM * 2;
  const size_t required = o_h + (size_t)N_TOK * 2 * HID * 2;  // ~202 MB
  if (ws_size < required) {
    fprintf(stderr, "kernel_launch: ws too small: have %zu need %zu\n", ws_size, required);
    return;
  }
  int* cnt        = (int*)(ws + o_ctrl);
  int* cursor     = cnt + 8;
  int* offs       = cnt + 16;
  int* tok_e      = (int*)(ws + o_toke);
  float* tok_g    = (float*)(ws + o_tokg);
  int* slot_token = (int*)(ws + o_stok);
  float* slot_gate= (float*)(ws + o_sgat);
  ushort* xb      = (ushort*)(ws + o_xb);
  ushort* w2T     = (ushort*)(ws + o_xb);   // aliased with xb
  ushort* w1T     = (ushort*)(ws + o_w1T);
  ushort* hbuf    = (ushort*)(ws + o_h);

  hipMemsetAsync(d_out, 0, (size_t)out_size * 4, stream);
  hipMemsetAsync(ws + o_ctrl, 0, 64, stream);

  xcvt_kernel<<<N_TOK * DIM / 8 / 256, 256, 0, stream>>>(x, xb);
  // w1 [E][D][H] -> w1T [E][H][D]
  transpose_cvt<DIM, HID><<<dim3(HID / 64, DIM / 64, NEXP), 256, 0, stream>>>(w1, w1T);

  router_kernel<<<N_TOK / 16, 256, 0, stream>>>(x, rw, rb, cnt, tok_e, tok_g);
  scan_kernel<<<1, 64, 0, stream>>>(cnt, offs, cursor);
  gather_kernel<<<N_TOK / 256, 256, 0, stream>>>(tok_e, tok_g, cursor, slot_token, slot_gate);

  gemm1_kernel<<<dim3(HID / 128, N_TOK / 128, NEXP), 256, 0, stream>>>(
      xb, w1T, b1, offs, slot_token, hbuf);

  // xb is dead now; build w2T in its place: w2 [E][H][D] -> w2T [E][D][H]
  transpose_cvt<HID, DIM><<<dim3(DIM / 64, HID / 64, NEXP), 256, 0, stream>>>(w2, w2T);

  gemm2_kernel<<<dim3(DIM / 128, N_TOK / 128, NEXP), 256, 0, stream>>>(
      hbuf, w2T, b2, offs, slot_token, slot_gate, out);
}